// Round 14
// baseline (932.632 us; speedup 1.0000x reference)
//
#include <hip/hip_runtime.h>
#include <stdint.h>

typedef unsigned short u16;
typedef float f32x4 __attribute__((ext_vector_type(4)));
typedef __bf16 bf16x8 __attribute__((ext_vector_type(8)));

#define B_ 4096
#define D_ 2048
#define U_ 2048
#define K_ 4096   // D + U
#define N_ 8192   // 4*U
#define NT_ 128   // K/32 K-tiles

__device__ __forceinline__ u16 f32_bf16(float f) {
  uint32_t u = __float_as_uint(f);
  u += 0x7FFFu + ((u >> 16) & 1u);
  return (u16)(u >> 16);
}
__device__ __forceinline__ float hsig(float x) {
  return fminf(fmaxf(0.2f * x + 0.5f, 0.0f), 1.0f);
}
__device__ __forceinline__ float ftanh(float x) {
  x = fminf(fmaxf(x, -15.0f), 15.0f);
  float e = __expf(2.0f * x);
  return (e - 1.0f) / (e + 1.0f);
}
__device__ __forceinline__ void gload16(const void* g, void* l) {
  __builtin_amdgcn_global_load_lds(
      (const __attribute__((address_space(1))) void*)g,
      (__attribute__((address_space(3))) void*)l,
      16, 0, 0);
}

// ---- cast A = [inputs | h_tm1] -> bf16 [4096][4096] ----
__global__ __launch_bounds__(256) void cast_a(const float* __restrict__ x,
                                              const float* __restrict__ h,
                                              u16* __restrict__ A) {
  int c = blockIdx.x * 256 + threadIdx.x;
  int m = c >> 9;
  int kc = (c & 511) << 3;
  const float* src = (kc < D_) ? (x + (size_t)m * D_ + kc)
                               : (h + (size_t)m * U_ + (kc - D_));
  float4 v0 = ((const float4*)src)[0];
  float4 v1 = ((const float4*)src)[1];
  u16 o[8] = { f32_bf16(v0.x), f32_bf16(v0.y), f32_bf16(v0.z), f32_bf16(v0.w),
               f32_bf16(v1.x), f32_bf16(v1.y), f32_bf16(v1.z), f32_bf16(v1.w) };
  *(uint4*)(A + (size_t)c * 8) = *(const uint4*)o;
}

// ---- cast + transpose + gate-interleave W -> Wt[n'][k] bf16 [8192][4096] ----
// n' = ublk*64 + g*16 + ul  where u = ublk*16 + ul, original col n = g*2048 + u
__global__ __launch_bounds__(256) void cast_wt(const float* __restrict__ kern,
                                               const float* __restrict__ rker,
                                               u16* __restrict__ Wt) {
  __shared__ u16 sW[64][68];
  const int t = threadIdx.x;
  const int bx = blockIdx.x;   // ublk 0..127
  const int by = blockIdx.y;   // k block 0..63
  const int k0 = by * 64;
  const float* src = (k0 < D_) ? kern : rker;
  const int krow0 = (k0 < D_) ? k0 : (k0 - D_);
#pragma unroll
  for (int i = 0; i < 4; ++i) {
    int c = i * 256 + t;
    int kl = c >> 4;
    int nq = c & 15;
    int g  = nq >> 2;
    int ul = (nq & 3) << 2;
    int n  = g * U_ + bx * 16 + ul;
    float4 v = *(const float4*)(src + (size_t)(krow0 + kl) * N_ + n);
    u16 p[4] = { f32_bf16(v.x), f32_bf16(v.y), f32_bf16(v.z), f32_bf16(v.w) };
    *(ushort4*)&sW[kl][g * 16 + ul] = *(const ushort4*)p;
  }
  __syncthreads();
#pragma unroll
  for (int j = 0; j < 2; ++j) {
    int c2 = j * 256 + t;
    int nl = c2 >> 3;
    int kc = c2 & 7;
    u16 p[8];
#pragma unroll
    for (int jj = 0; jj < 8; ++jj) p[jj] = sW[kc * 8 + jj][nl];
    *(uint4*)(Wt + ((size_t)bx * 64 + nl) * K_ + k0 + kc * 8) = *(const uint4*)p;
  }
}

// == 256x256 GEMM: 4-parity BK=32, intra-phase read/MFMA interleave ==
// LDS: 4 parities x (A 16K + B 16K) = 128 KiB, 1 block/CU (8 waves, 2/SIMD).
// 512-thr block -> hard cap 131072/512 = 256 combined regs/wave; all 12
// fragment reads are consumed WITHIN their phase (no cross-phase liveness)
// so the compiler cannot software-pipeline -> no spill (r12's failure mode
// excluded by construction). phys_chunk = logical ^ ((row>>1)&3): 0-conflict.
//
// Phase p: [bar][fence][read av01+bv0-3 (6)][STAGE p+2][VMW(4)][lgkm0+SB]
//   [read av23][G8(0,1)][lgkm0+SB][read av45][G8(2,3)][lgkm0+SB]
//   [read av67][G8(4,5)][lgkm0+SB][G8(6,7)]
// The av23/45/67 reads are serviced DURING the preceding 8-MFMA bursts, so
// each lgkm0 is ~free; LDS service overlaps MFMA issue (r6's serial gap).
//
// RAW: parity p staged @p-2, drained by every wave's VMW(4) @p-1 (queue
// [stage p, stage p+1] -> drain to 4 = stage p done) before barrier(p);
// reads @p are after barrier(p) + compiler fence (r9/r13-proven no-hoist).
// WAR: stage(p+2) overwrites parity p-2; its readers finished (lgkm-landed,
// consumed by G8s) before barrier(p-1) < barrier(p) < stage issue.
#define LDSA(par) ((par) * 32768)
#define LDSB(par) ((par) * 32768 + 16384)

#define STAGE4(par, t) do { \
  const u16* ga_ = Ab + (size_t)grow * K_ + (t) * 32 + gch8; \
  const u16* gb_ = Bb + (size_t)grow * K_ + (t) * 32 + gch8; \
  char* la_ = ldsc + LDSA(par) + wid * 1024; \
  char* lb_ = ldsc + LDSB(par) + wid * 1024; \
  gload16(ga_, la_); \
  gload16(ga_ + (size_t)128 * K_, la_ + 8192); \
  gload16(gb_, lb_); \
  gload16(gb_ + (size_t)128 * K_, lb_ + 8192); \
} while (0)

#define VMW(n) asm volatile("s_waitcnt vmcnt(" #n ")" ::: "memory")
#define LGKM0_SB do { \
  asm volatile("s_waitcnt lgkmcnt(0)" ::: "memory"); \
  __builtin_amdgcn_sched_barrier(0); \
} while (0)
#define MFMA16 __builtin_amdgcn_mfma_f32_16x16x32_bf16

#define G8(mA, mB) \
  acc[mA][0] = MFMA16(av[mA], bv[0], acc[mA][0], 0, 0, 0); \
  acc[mA][1] = MFMA16(av[mA], bv[1], acc[mA][1], 0, 0, 0); \
  acc[mA][2] = MFMA16(av[mA], bv[2], acc[mA][2], 0, 0, 0); \
  acc[mA][3] = MFMA16(av[mA], bv[3], acc[mA][3], 0, 0, 0); \
  acc[mB][0] = MFMA16(av[mB], bv[0], acc[mB][0], 0, 0, 0); \
  acc[mB][1] = MFMA16(av[mB], bv[1], acc[mB][1], 0, 0, 0); \
  acc[mB][2] = MFMA16(av[mB], bv[2], acc[mB][2], 0, 0, 0); \
  acc[mB][3] = MFMA16(av[mB], bv[3], acc[mB][3], 0, 0, 0);

#define PHASE(par, STAGE_STMT, VMW_STMT) do { \
  __builtin_amdgcn_s_barrier(); \
  asm volatile("" ::: "memory"); \
  const char* pa_ = ldsc + LDSA(par) + aob; \
  const char* pb_ = ldsc + LDSB(par) + bob; \
  bv[0] = *(const bf16x8*)(pb_); \
  bv[1] = *(const bf16x8*)(pb_ + 1024); \
  bv[2] = *(const bf16x8*)(pb_ + 2048); \
  bv[3] = *(const bf16x8*)(pb_ + 3072); \
  av[0] = *(const bf16x8*)(pa_); \
  av[1] = *(const bf16x8*)(pa_ + 1024); \
  STAGE_STMT; \
  VMW_STMT; \
  LGKM0_SB; \
  av[2] = *(const bf16x8*)(pa_ + 2048); \
  av[3] = *(const bf16x8*)(pa_ + 3072); \
  __builtin_amdgcn_s_setprio(1); \
  G8(0, 1); \
  LGKM0_SB; \
  av[4] = *(const bf16x8*)(pa_ + 4096); \
  av[5] = *(const bf16x8*)(pa_ + 5120); \
  G8(2, 3); \
  LGKM0_SB; \
  av[6] = *(const bf16x8*)(pa_ + 6144); \
  av[7] = *(const bf16x8*)(pa_ + 7168); \
  G8(4, 5); \
  LGKM0_SB; \
  G8(6, 7); \
  __builtin_amdgcn_s_setprio(0); \
} while (0)

__global__ __launch_bounds__(512, 2) void lstm_gemm(const u16* __restrict__ A,
                                                    const u16* __restrict__ Wt,
                                                    const float* __restrict__ c_prev,
                                                    float* __restrict__ out) {
  __shared__ __align__(16) u16 lds[65536];   // 128 KiB
  char* ldsc = (char*)lds;
  const int tid  = threadIdx.x;
  const int lane = tid & 63;
  const int wid  = tid >> 6;
  const int wr   = wid >> 2;   // 0..1: 128-row slice
  const int wcn  = wid & 3;    // 0..3: 64-col slice (4 gates x 16 u)
  const int fr   = lane & 15;
  const int fq   = lane >> 4;

  // XCD-aware swizzle (512 % 8 == 0 -> bijective)
  const int orig = blockIdx.x;
  const int wg   = ((orig & 7) << 6) | (orig >> 3);
  const int bm   = wg & 15;
  const int bn   = wg >> 4;

  const u16* Ab = A  + (size_t)bm * 256 * K_;
  const u16* Bb = Wt + (size_t)bn * 256 * K_;

  // staging: thread -> (row, swizzled 16B chunk) of a [256][32] tile slice
  const int grow = tid >> 2;                                 // 0..127
  const int gch8 = (((tid & 3) ^ ((grow >> 1) & 3)) << 3);   // element offset
  // fragment reads: logical chunk fq at row r lives at fq ^ ((r>>1)&3)
  const int csw = (fq ^ ((fr >> 1) & 3)) << 4;
  const int aob = (wr * 128 + fr) * 64 + csw;   // + m*1024
  const int bob = (wcn * 64 + fr) * 64 + csw;   // + n*1024

  f32x4 acc[8][4] = {};   // [m-frag][gate] -> AGPRs
  bf16x8 av[8], bv[4];

  // ---- prologue: stage tiles 0,1; drain tile0 (queue 8 -> 4) ----
  STAGE4(0, 0);
  STAGE4(1, 1);
  VMW(4);

  for (int tb = 0; tb < NT_; tb += 4) {
    PHASE(0, { STAGE4(2, tb + 2); }, { VMW(4); });
    PHASE(1, { STAGE4(3, tb + 3); }, { VMW(4); });
    if (tb + 4 < NT_) {
      PHASE(2, { STAGE4(0, tb + 4); }, { VMW(4); });
      PHASE(3, { STAGE4(1, tb + 5); }, { VMW(4); });
    } else {
      PHASE(2, {}, { VMW(0); });   // drain tail stage (parity 3, tile 127)
      PHASE(3, {}, {});
    }
  }

  // ---- fused LSTM epilogue (C/D 16x16: col=fr, row=fq*4+r) ----
  const int u  = (bn * 4 + wcn) * 16 + fr;
  const size_t BU = (size_t)B_ * U_;
#pragma unroll
  for (int mi = 0; mi < 8; ++mi) {
#pragma unroll
    for (int r = 0; r < 4; ++r) {
      int row = bm * 256 + wr * 128 + mi * 16 + fq * 4 + r;
      float zi = acc[mi][0][r], zf = acc[mi][1][r];
      float zc = acc[mi][2][r], zo = acc[mi][3][r];
      float iv = hsig(zi), fv = hsig(zf), ov = hsig(zo);
      size_t off = (size_t)row * U_ + u;
      float cp = c_prev[off];
      float cv = fv * cp + iv * ftanh(zc);
      float hv = ov * ftanh(cv);
      out[off]          = hv;
      out[BU + off]     = hv;
      out[2 * BU + off] = cv;
    }
  }
}

extern "C" void kernel_launch(void* const* d_in, const int* in_sizes, int n_in,
                              void* d_out, int out_size, void* d_ws, size_t ws_size,
                              hipStream_t stream) {
  const float* x  = (const float*)d_in[0];
  const float* h  = (const float*)d_in[1];
  const float* cp = (const float*)d_in[2];
  const float* kk = (const float*)d_in[3];
  const float* rk = (const float*)d_in[4];
  float* out = (float*)d_out;

  const size_t bytesA  = (size_t)B_ * K_ * 2;   // 32 MiB
  const size_t bytesWt = (size_t)N_ * K_ * 2;   // 64 MiB
  if (ws_size < bytesA + bytesWt) return;

  u16* Aws = (u16*)d_ws;
  u16* Wt  = (u16*)((char*)d_ws + bytesA);

  cast_a<<<(B_ * K_ / 8) / 256, 256, 0, stream>>>(x, h, Aws);
  cast_wt<<<dim3(N_ / 64, K_ / 64), 256, 0, stream>>>(kk, rk, Wt);
  lstm_gemm<<<dim3(512), dim3(512), 0, stream>>>(Aws, Wt, cp, out);
}